// Round 1
// baseline (1243.464 us; speedup 1.0000x reference)
//
#include <hip/hip_runtime.h>
#include <stdint.h>

#define E_TOTAL 640000
#define EPS_LN 1e-5f

typedef short short8 __attribute__((ext_vector_type(8)));
typedef float f32x4 __attribute__((ext_vector_type(4)));
typedef float f32x4v __attribute__((ext_vector_type(4)));

// f32 -> bf16 round-to-nearest-even (inputs are finite)
__device__ __forceinline__ short bfr(float f) {
    uint32_t u = __builtin_bit_cast(uint32_t, f);
    u += 0x7fffu + ((u >> 16) & 1u);
    return (short)(u >> 16);
}

// load 8 consecutive f32 and pack to bf16x8 (A-fragment)
__device__ __forceinline__ short8 cvt8(const float* __restrict__ p) {
    f32x4v x = *(const f32x4v*)p;
    f32x4v y = *(const f32x4v*)(p + 4);
    short8 r;
    r[0] = bfr(x[0]); r[1] = bfr(x[1]); r[2] = bfr(x[2]); r[3] = bfr(x[3]);
    r[4] = bfr(y[0]); r[5] = bfr(y[1]); r[6] = bfr(y[2]); r[7] = bfr(y[3]);
    return r;
}

// swizzled offset (in shorts) within a 32x256 bf16 slice: 16B-chunk xor row&7
__device__ __forceinline__ int hoff(int row, int col) {
    int c = col >> 3;
    int cs = c ^ (row & 7);
    return row * 256 + cs * 8 + (col & 7);
}

// ---------------------------------------------------------------------------
// Prep: convert W1/W2/W3 f32 -> bf16 in MFMA B-fragment order.
// Layout per layer: flat[((n_tile*(K/32) + k_step)*64 + lane)*8 + j]
//   = W[k_step*32 + (lane>>4)*8 + j][n_tile*16 + (lane&15)]
// Sizes (elements): W1 98304, W2 65536, W3 32768  -> total 196608
// ---------------------------------------------------------------------------
__global__ void prep_weights(const float* __restrict__ W1,
                             const float* __restrict__ W2,
                             const float* __restrict__ W3,
                             short* __restrict__ wt) {
    int i = blockIdx.x * 256 + threadIdx.x;   // exact grid: 768*256 = 196608
    const float* W;
    int K, N, base, idx = i;
    if (idx < 98304)              { W = W1; K = 384; N = 256; base = 0; }
    else if (idx < 98304 + 65536) { W = W2; K = 256; N = 256; base = 98304; idx -= 98304; }
    else                          { W = W3; K = 256; N = 128; base = 98304 + 65536; idx -= 98304 + 65536; }
    int j    = idx & 7;
    int lane = (idx >> 3) & 63;
    int rest = idx >> 9;
    int nk   = K / 32;
    int ks   = rest % nk;
    int u    = rest / nk;
    int k = ks * 32 + (lane >> 4) * 8 + j;
    int n = u * 16 + (lane & 15);
    wt[base + idx] = bfr(W[k * N + n]);
}

// ---------------------------------------------------------------------------
// Fused edge MLP + LayerNorm. 4 waves/block, each wave owns 32 edges.
// No barriers: each wave uses a private LDS slice for the h1/h2
// C-layout -> A-layout round trip.
// ---------------------------------------------------------------------------
__global__ __launch_bounds__(256, 2)
void edge_mlp(const float* __restrict__ node_feat,
              const float* __restrict__ edge_feat,
              const int*   __restrict__ eidx,
              const short* __restrict__ wt,
              const float* __restrict__ b1,
              const float* __restrict__ b2,
              const float* __restrict__ b3,
              const float* __restrict__ gamma,
              const float* __restrict__ beta,
              float* __restrict__ out) {
    __shared__ short hbuf[4][32 * 256];   // 64 KiB -> 2 blocks/CU

    const int tid  = threadIdx.x;
    const int wave = tid >> 6;
    const int lane = tid & 63;
    const int quad = lane >> 4;
    const int l15  = lane & 15;
    const int m_base = blockIdx.x * 128 + wave * 32;
    short* hb = hbuf[wave];

    // edge rows this lane supplies A-fragments for (two 16-row m-tiles)
    const int r0 = m_base + l15;
    const int r1 = r0 + 16;
    const int s0 = eidx[r0],           s1 = eidx[r1];
    const int d0 = eidx[E_TOTAL + r0], d1 = eidx[E_TOTAL + r1];

    const short* w1 = wt;
    const short* w2 = wt + 98304;
    const short* w3 = wt + 98304 + 65536;

    f32x4 acc[2][16];

    // ================= layer 1: [32,384] @ [384,256] + b1, relu ============
    #pragma unroll
    for (int u = 0; u < 16; ++u) {
        float bv = b1[u * 16 + l15];
        acc[0][u] = f32x4{bv, bv, bv, bv};
        acc[1][u] = acc[0][u];
    }
    #pragma unroll 1
    for (int ks = 0; ks < 12; ++ks) {
        const float *p0, *p1;
        if (ks < 4)      { p0 = node_feat + (size_t)s0 * 128; p1 = node_feat + (size_t)s1 * 128; }
        else if (ks < 8) { p0 = node_feat + (size_t)d0 * 128; p1 = node_feat + (size_t)d1 * 128; }
        else             { p0 = edge_feat + (size_t)r0 * 128; p1 = edge_feat + (size_t)r1 * 128; }
        const int ko = (ks & 3) * 32 + quad * 8;
        short8 a0 = cvt8(p0 + ko);
        short8 a1 = cvt8(p1 + ko);
        const short* wb = w1 + ks * 512 + lane * 8;   // u-stride = 12*64*8 = 6144
        #pragma unroll
        for (int u = 0; u < 16; ++u) {
            short8 b = *(const short8*)(wb + u * 6144);
            acc[0][u] = __builtin_amdgcn_mfma_f32_16x16x32_bf16(a0, b, acc[0][u], 0, 0, 0);
            acc[1][u] = __builtin_amdgcn_mfma_f32_16x16x32_bf16(a1, b, acc[1][u], 0, 0, 0);
        }
    }
    // relu -> bf16 -> LDS (C-layout scatter, swizzled)
    #pragma unroll
    for (int t = 0; t < 2; ++t)
        #pragma unroll
        for (int u = 0; u < 16; ++u)
            #pragma unroll
            for (int r = 0; r < 4; ++r) {
                float v = fmaxf(acc[t][u][r], 0.0f);
                hb[hoff(t * 16 + quad * 4 + r, u * 16 + l15)] = bfr(v);
            }

    // ================= layer 2: [32,256] @ [256,256] + b2, relu ============
    #pragma unroll
    for (int u = 0; u < 16; ++u) {
        float bv = b2[u * 16 + l15];
        acc[0][u] = f32x4{bv, bv, bv, bv};
        acc[1][u] = acc[0][u];
    }
    #pragma unroll 1
    for (int ks = 0; ks < 8; ++ks) {
        short8 a0 = *(const short8*)&hb[hoff(l15,      ks * 32 + quad * 8)];
        short8 a1 = *(const short8*)&hb[hoff(16 + l15, ks * 32 + quad * 8)];
        const short* wb = w2 + ks * 512 + lane * 8;   // u-stride = 8*64*8 = 4096
        #pragma unroll
        for (int u = 0; u < 16; ++u) {
            short8 b = *(const short8*)(wb + u * 4096);
            acc[0][u] = __builtin_amdgcn_mfma_f32_16x16x32_bf16(a0, b, acc[0][u], 0, 0, 0);
            acc[1][u] = __builtin_amdgcn_mfma_f32_16x16x32_bf16(a1, b, acc[1][u], 0, 0, 0);
        }
    }
    // relu -> bf16 -> LDS (h2 overwrites h1; all reads precede writes by dataflow)
    #pragma unroll
    for (int t = 0; t < 2; ++t)
        #pragma unroll
        for (int u = 0; u < 16; ++u)
            #pragma unroll
            for (int r = 0; r < 4; ++r) {
                float v = fmaxf(acc[t][u][r], 0.0f);
                hb[hoff(t * 16 + quad * 4 + r, u * 16 + l15)] = bfr(v);
            }

    // ================= layer 3: [32,256] @ [256,128] + b3 ==================
    #pragma unroll
    for (int u = 0; u < 8; ++u) {
        float bv = b3[u * 16 + l15];
        acc[0][u] = f32x4{bv, bv, bv, bv};
        acc[1][u] = acc[0][u];
    }
    #pragma unroll 1
    for (int ks = 0; ks < 8; ++ks) {
        short8 a0 = *(const short8*)&hb[hoff(l15,      ks * 32 + quad * 8)];
        short8 a1 = *(const short8*)&hb[hoff(16 + l15, ks * 32 + quad * 8)];
        const short* wb = w3 + ks * 512 + lane * 8;   // u-stride = 4096
        #pragma unroll
        for (int u = 0; u < 8; ++u) {
            short8 b = *(const short8*)(wb + u * 4096);
            acc[0][u] = __builtin_amdgcn_mfma_f32_16x16x32_bf16(a0, b, acc[0][u], 0, 0, 0);
            acc[1][u] = __builtin_amdgcn_mfma_f32_16x16x32_bf16(a1, b, acc[1][u], 0, 0, 0);
        }
    }

    // ================= LayerNorm(128) + store ==============================
    float gam[8], bet[8];
    #pragma unroll
    for (int u = 0; u < 8; ++u) { gam[u] = gamma[u * 16 + l15]; bet[u] = beta[u * 16 + l15]; }

    #pragma unroll
    for (int t = 0; t < 2; ++t) {
        float s[4] = {0, 0, 0, 0}, q[4] = {0, 0, 0, 0};
        #pragma unroll
        for (int u = 0; u < 8; ++u)
            #pragma unroll
            for (int r = 0; r < 4; ++r) {
                float v = acc[t][u][r];
                s[r] += v; q[r] += v * v;
            }
        // reduce across the 16 lanes holding one row (xor 1,2,4,8 stays in-group)
        #pragma unroll
        for (int m = 1; m < 16; m <<= 1) {
            #pragma unroll
            for (int r = 0; r < 4; ++r) {
                s[r] += __shfl_xor(s[r], m, 64);
                q[r] += __shfl_xor(q[r], m, 64);
            }
        }
        #pragma unroll
        for (int r = 0; r < 4; ++r) {
            float mu  = s[r] * (1.0f / 128.0f);
            float var = q[r] * (1.0f / 128.0f) - mu * mu;
            float inv = rsqrtf(var + EPS_LN);
            int grow = m_base + t * 16 + quad * 4 + r;
            float* orow = out + (size_t)grow * 128;
            #pragma unroll
            for (int u = 0; u < 8; ++u)
                orow[u * 16 + l15] = (acc[t][u][r] - mu) * inv * gam[u] + bet[u];
        }
    }
}

extern "C" void kernel_launch(void* const* d_in, const int* in_sizes, int n_in,
                              void* d_out, int out_size, void* d_ws, size_t ws_size,
                              hipStream_t stream) {
    const float* node_feat = (const float*)d_in[0];
    const float* edge_feat = (const float*)d_in[1];
    const int*   eidx      = (const int*)  d_in[2];
    const float* W1        = (const float*)d_in[3];
    const float* b1        = (const float*)d_in[4];
    const float* W2        = (const float*)d_in[5];
    const float* b2        = (const float*)d_in[6];
    const float* W3        = (const float*)d_in[7];
    const float* b3        = (const float*)d_in[8];
    const float* gamma     = (const float*)d_in[9];
    const float* beta      = (const float*)d_in[10];
    float* out = (float*)d_out;
    short* wt  = (short*)d_ws;   // 196608 bf16 = 393216 bytes

    prep_weights<<<768, 256, 0, stream>>>(W1, W2, W3, wt);
    edge_mlp<<<E_TOTAL / 128, 256, 0, stream>>>(node_feat, edge_feat, eidx, wt,
                                                b1, b2, b3, gamma, beta, out);
}